// Round 1
// 352.004 us; speedup vs baseline: 1.0911x; 1.0911x over previous
//
#include <hip/hip_runtime.h>
#include <hip/hip_bf16.h>

// 2-layer GCN, HID=16 space for both aggregations (Ahat·(h@W2) == (Ahat·h)@W2),
// edge weight dinv[s]*dinv[d] factored into per-node feature pre-scaling.
// Adjacency via two-level LDS counting sort (R5: ~153k global RMW vs 3.2M).
// R6: gemm1 (x@W1) via MFMA bf16.
// R7: binA/binB were latency-bound at 13% occupancy (391 blocks, VALUBusy 1.9%,
// hbm 11% of peak). binA: EPB 8192->4096, 512 thr, edges held in registers
// across phases (one global read of src/dst instead of two of dst).
// binB: 1024 thr/block. Both now ~24 waves/CU instead of ~6.

#define BSH 8                 // bucket = dst >> 8  (256 nodes per bucket)
#define BCAP 9216             // slots per bucket region (mean ~8184, sd ~90)
#define MAXB 512              // LDS table size; requires nbuckets <= 512
#define OVF_CAP 8192
#define EPB 4096              // edges per binA block

typedef __attribute__((ext_vector_type(8))) short bf16x8;
typedef __attribute__((ext_vector_type(4))) float f32x4;

__device__ __forceinline__ short f2b(float f) {
    __hip_bfloat16 h = __float2bfloat16(f);   // RNE
    return *reinterpret_cast<short*>(&h);
}

__global__ void seed_k(int* __restrict__ gcur, int nbuckets, int* __restrict__ ovf_cnt) {
    int i = blockIdx.x * blockDim.x + threadIdx.x;
    if (i < nbuckets) gcur[i] = i * BCAP;
    if (i == 0) *ovf_cnt = 0;
}

// Pass A: LDS bucket histogram -> one global atomicAdd per (block,bucket) ->
// scatter packed (src<<8|dst_low) into padded bucket regions.
// Edges live in registers across the 3 phases (8 per thread, unrolled).
__global__ __launch_bounds__(512) void binA(
        const int* __restrict__ src, const int* __restrict__ dst,
        int* __restrict__ gcur, int* __restrict__ padded,
        int2* __restrict__ ovf, int* __restrict__ ovf_cnt, int E) {
    __shared__ int hist[MAXB], gb[MAXB];
    int tid = threadIdx.x;
    int e0 = blockIdx.x * EPB;
    int e1 = min(e0 + EPB, E);
    if (tid < MAXB) hist[tid] = 0;
    __syncthreads();
    int rs[8], rd[8];
#pragma unroll
    for (int u = 0; u < 8; ++u) {
        int i = e0 + tid + u * 512;
        if (i < e1) {
            rd[u] = dst[i];
            rs[u] = src[i];
            atomicAdd(&hist[rd[u] >> BSH], 1);
        }
    }
    __syncthreads();
    if (tid < MAXB) {
        int h = hist[tid];
        gb[tid] = h ? atomicAdd(&gcur[tid], h) : 0;
        hist[tid] = 0;
    }
    __syncthreads();
#pragma unroll
    for (int u = 0; u < 8; ++u) {
        int i = e0 + tid + u * 512;
        if (i < e1) {
            int s = rs[u], d = rd[u];
            int b = d >> BSH;
            int r = atomicAdd(&hist[b], 1);
            int pos = gb[b] + r;
            if (pos < (b + 1) * BCAP) {
                padded[pos] = (s << BSH) | (d & ((1 << BSH) - 1));
            } else {
                int k = atomicAdd(ovf_cnt, 1);
                if (k < OVF_CAP) ovf[k] = make_int2(s, d);
            }
        }
    }
}

// Pass B: per-bucket LDS counting sort by dst_low8 -> sorted CSR + degrees.
// 1024 threads/block (was 256): 16 waves/block for latency hiding.
__global__ __launch_bounds__(1024) void binB(
        const int* __restrict__ gcur, int* __restrict__ padded,
        int2* __restrict__ og, int* __restrict__ deg, int n) {
    __shared__ int bins[256], scanb[256], sA[256];
    __shared__ int sorted[BCAP];
    int k = blockIdx.x, tid = threadIdx.x;
    int base = k * BCAP;
    int cnt = gcur[k] - base;
    if (cnt > BCAP) cnt = BCAP;
    if (cnt < 0) cnt = 0;
    if (tid < 256) bins[tid] = 0;
    __syncthreads();
    for (int i = tid; i < cnt; i += 1024)
        atomicAdd(&bins[padded[base + i] & 255], 1);
    __syncthreads();
    if (tid < 256) sA[tid] = bins[tid];
    __syncthreads();
    for (int d = 1; d < 256; d <<= 1) {
        int v = 0, a = 0;
        if (tid < 256) {
            v = sA[tid];
            a = (tid >= d) ? sA[tid - d] : 0;
        }
        __syncthreads();
        if (tid < 256) sA[tid] = v + a;
        __syncthreads();
    }
    if (tid < 256) {
        int excl = sA[tid] - bins[tid];
        scanb[tid] = excl;
        int node = (k << BSH) + tid;
        if (node < n) {
            og[node] = make_int2(base + excl, bins[tid]);
            deg[node] = bins[tid];
        }
        bins[tid] = 0;
    }
    __syncthreads();
    for (int i = tid; i < cnt; i += 1024) {
        int v = padded[base + i];
        int lo = v & 255;
        int r = atomicAdd(&bins[lo], 1);
        sorted[scanb[lo] + r] = v >> BSH;
    }
    __syncthreads();
    for (int i = tid; i < cnt; i += 1024) padded[base + i] = sorted[i];
}

__global__ void fixdeg_k(const int2* __restrict__ ovf, const int* __restrict__ ovf_cnt,
                         int* __restrict__ deg) {
    int c = *ovf_cnt;
    if (c > OVF_CAP) c = OVF_CAP;
    for (int i = blockIdx.x * blockDim.x + threadIdx.x; i < c;
         i += gridDim.x * blockDim.x)
        atomicAdd(&deg[ovf[i].y], 1);
}

__global__ void dinv_k(const int* __restrict__ deg, float* __restrict__ dinv, int n) {
    int i = blockIdx.x * blockDim.x + threadIdx.x;
    if (i < n) dinv[i] = rsqrtf((float)deg[i] + 1.0f);  // +1 = self-loop
}

// t1d = (x @ W1) * dinv, via MFMA bf16. Block = 256 thr = 4 waves = 64 nodes.
// A-frag: A[m=lane&15][k=quad*8+j]; B-frag: B[n=lane&15][k=quad*8+j];
// C/D:   col(n)=lane&15, row(m)=quad*4+reg   [verified layouts per guide m89/m91]
__global__ __launch_bounds__(256) void gemm1_mfma(
        const float* __restrict__ x, const float* __restrict__ W1,
        const float* __restrict__ dinv, float* __restrict__ t1d, int n) {
    __shared__ __align__(16) short xs[64 * 264];  // 64 rows, stride 264 bf16 (16B-aligned, bank-safe)
    __shared__ short w1s[256 * 16];
    int tid = threadIdx.x;
    int base = blockIdx.x * 64;
    int rows = n - base; if (rows > 64) rows = 64;

    for (int i = tid; i < 4096; i += 256) w1s[i] = f2b(W1[i]);
    for (int i = tid; i < 4096; i += 256) {        // 4096 float4 = 64 rows x 64
        int r = i >> 6, c = i & 63;
        if (r < rows) {
            float4 v = ((const float4*)(x + (size_t)(base + r) * 256))[c];
            short4 b;
            b.x = f2b(v.x); b.y = f2b(v.y); b.z = f2b(v.z); b.w = f2b(v.w);
            *(short4*)&xs[r * 264 + c * 4] = b;
        }
    }
    __syncthreads();

    int lane = tid & 63, wave = tid >> 6;
    int q = lane >> 4, m = lane & 15;

    bf16x8 bfrag[8];
#pragma unroll
    for (int t = 0; t < 8; ++t)
#pragma unroll
        for (int j = 0; j < 8; ++j)
            bfrag[t][j] = w1s[(t * 32 + q * 8 + j) * 16 + m];

    f32x4 acc = {0.f, 0.f, 0.f, 0.f};
    int arow = wave * 16 + m;
#pragma unroll
    for (int t = 0; t < 8; ++t) {
        bf16x8 a = *(const bf16x8*)&xs[arow * 264 + t * 32 + q * 8];
        acc = __builtin_amdgcn_mfma_f32_16x16x32_bf16(a, bfrag[t], acc, 0, 0, 0);
    }
#pragma unroll
    for (int r = 0; r < 4; ++r) {
        int node = base + wave * 16 + q * 4 + r;
        if (node < n)
            t1d[(size_t)node * 16 + m] = acc[r] * dinv[node];
    }
}

// S[d] = feat[d] + sum_{CSR} feat[src]   (unscaled; bias/relu applied later)
__global__ __launch_bounds__(256) void agg_k(
        const int2* __restrict__ og, const int* __restrict__ padded,
        const float* __restrict__ feat, float* __restrict__ S, int n) {
    int node = blockIdx.x * 64 + (threadIdx.x >> 2);
    int q    = threadIdx.x & 3;
    if (node >= n) return;
    const float4* f4 = (const float4*)feat;
    float4 acc = f4[(size_t)node * 4 + q];  // self-loop term
    int2 o = og[node];
    int b = o.x, c = o.y, j = 0;
    for (; j + 4 <= c; j += 4) {
        int s0 = padded[b + j],     s1 = padded[b + j + 1];
        int s2 = padded[b + j + 2], s3 = padded[b + j + 3];
        float4 v0 = f4[(size_t)s0 * 4 + q];
        float4 v1 = f4[(size_t)s1 * 4 + q];
        float4 v2 = f4[(size_t)s2 * 4 + q];
        float4 v3 = f4[(size_t)s3 * 4 + q];
        acc.x += (v0.x + v1.x) + (v2.x + v3.x);
        acc.y += (v0.y + v1.y) + (v2.y + v3.y);
        acc.z += (v0.z + v1.z) + (v2.z + v3.z);
        acc.w += (v0.w + v1.w) + (v2.w + v3.w);
    }
    for (; j < c; ++j) {
        float4 v = f4[(size_t)padded[b + j] * 4 + q];
        acc.x += v.x; acc.y += v.y; acc.z += v.z; acc.w += v.w;
    }
    ((float4*)S)[(size_t)node * 4 + q] = acc;
}

__global__ void fixS_k(const int2* __restrict__ ovf, const int* __restrict__ ovf_cnt,
                       const float* __restrict__ feat, float* __restrict__ S) {
    int c = *ovf_cnt;
    if (c > OVF_CAP) c = OVF_CAP;
    for (int i = blockIdx.x * blockDim.x + threadIdx.x; i < c;
         i += gridDim.x * blockDim.x) {
        int2 e = ovf[i];
        for (int h = 0; h < 16; ++h)
            atomicAdd(&S[(size_t)e.y * 16 + h], feat[(size_t)e.x * 16 + h]);
    }
}

// hd[i] = relu(b1 + dinv[i]*S[i]) * dinv[i]   (in place)
__global__ void relu_k(float* __restrict__ S, const float* __restrict__ dinv,
                       const float* __restrict__ b1, int n) {
    int node = blockIdx.x * blockDim.x + threadIdx.x;
    if (node >= n) return;
    float di = dinv[node];
    float4* row = (float4*)S + (size_t)node * 4;
    const float4* b4 = (const float4*)b1;
#pragma unroll
    for (int q = 0; q < 4; ++q) {
        float4 v = row[q], b = b4[q];
        v.x = fmaxf(b.x + di * v.x, 0.f) * di;
        v.y = fmaxf(b.y + di * v.y, 0.f) * di;
        v.z = fmaxf(b.z + di * v.z, 0.f) * di;
        v.w = fmaxf(b.w + di * v.w, 0.f) * di;
        row[q] = v;
    }
}

// logits = b2 + (dinv*S2) @ W2; out = logits - logsumexp
__global__ __launch_bounds__(256) void final_k(
        const float* __restrict__ S2, const float* __restrict__ dinv,
        const float* __restrict__ W2, const float* __restrict__ b2,
        float* __restrict__ out, int n) {
    __shared__ float W2s[16 * 40];
    __shared__ float b2s[40];
    for (int i = threadIdx.x; i < 640; i += 256) W2s[i] = W2[i];
    if (threadIdx.x < 40) b2s[threadIdx.x] = b2[threadIdx.x];
    __syncthreads();
    int node = blockIdx.x * blockDim.x + threadIdx.x;
    if (node >= n) return;
    float di = dinv[node];
    float g[16];
    const float4* a4 = (const float4*)(S2 + (size_t)node * 16);
    float4 t0 = a4[0], t1 = a4[1], t2 = a4[2], t3 = a4[3];
    g[0]=di*t0.x; g[1]=di*t0.y; g[2]=di*t0.z; g[3]=di*t0.w;
    g[4]=di*t1.x; g[5]=di*t1.y; g[6]=di*t1.z; g[7]=di*t1.w;
    g[8]=di*t2.x; g[9]=di*t2.y; g[10]=di*t2.z; g[11]=di*t2.w;
    g[12]=di*t3.x; g[13]=di*t3.y; g[14]=di*t3.z; g[15]=di*t3.w;
    float lg[40];
    float mx = -1e30f;
#pragma unroll
    for (int j = 0; j < 40; ++j) {
        float acc = b2s[j];
#pragma unroll
        for (int k = 0; k < 16; ++k) acc += g[k] * W2s[k * 40 + j];
        lg[j] = acc;
        mx = fmaxf(mx, acc);
    }
    float sum = 0.f;
#pragma unroll
    for (int j = 0; j < 40; ++j) sum += __expf(lg[j] - mx);
    float lse = mx + logf(sum);
    float4* o4 = (float4*)(out + (size_t)node * 40);
#pragma unroll
    for (int j = 0; j < 10; ++j) {
        float4 v;
        v.x = lg[4 * j + 0] - lse;
        v.y = lg[4 * j + 1] - lse;
        v.z = lg[4 * j + 2] - lse;
        v.w = lg[4 * j + 3] - lse;
        o4[j] = v;
    }
}

extern "C" void kernel_launch(void* const* d_in, const int* in_sizes, int n_in,
                              void* d_out, int out_size, void* d_ws, size_t ws_size,
                              hipStream_t stream) {
    const float* x  = (const float*)d_in[0];
    const int*   ei = (const int*)d_in[1];
    const float* W1 = (const float*)d_in[2];
    const float* b1 = (const float*)d_in[3];
    const float* W2 = (const float*)d_in[4];
    const float* b2 = (const float*)d_in[5];

    int n = in_sizes[0] / 256;
    int E = in_sizes[1] / 2;
    const int* srcp = ei;       // edge_index[0]
    const int* dstp = ei + E;   // edge_index[1]

    int nbuckets = (n + 255) >> BSH;   // <= MAXB

    int2*  og      = (int2*)d_ws;                       // 2n words
    int*   deg     = (int*)d_ws + 2 * (size_t)n;        // n
    float* dinv    = (float*)((int*)d_ws + 3 * (size_t)n);  // n
    int*   gcur    = (int*)d_ws + 4 * (size_t)n;        // MAXB
    int*   ovf_cnt = gcur + MAXB;                       // 16
    int2*  ovf     = (int2*)(ovf_cnt + 16);             // 2*OVF_CAP words
    float* bufA    = (float*)(ovf_cnt + 16 + 2 * OVF_CAP);  // 16n : t1d, later S2
    float* bufB    = bufA + 16 * (size_t)n;                 // 16n : S1 -> hd
    int*   padded  = (int*)(bufB + 16 * (size_t)n);     // nbuckets*BCAP
    float* out     = (float*)d_out;

    int gb_n = (n + 255) / 256;

    seed_k    <<<(nbuckets + 255) / 256, 256, 0, stream>>>(gcur, nbuckets, ovf_cnt);
    binA      <<<(E + EPB - 1) / EPB, 512, 0, stream>>>(srcp, dstp, gcur, padded, ovf, ovf_cnt, E);
    binB      <<<nbuckets, 1024, 0, stream>>>(gcur, padded, og, deg, n);
    fixdeg_k  <<<16, 256, 0, stream>>>(ovf, ovf_cnt, deg);
    dinv_k    <<<gb_n, 256, 0, stream>>>(deg, dinv, n);
    gemm1_mfma<<<(n + 63) / 64, 256, 0, stream>>>(x, W1, dinv, bufA, n);
    agg_k     <<<(n + 63) / 64, 256, 0, stream>>>(og, padded, bufA, bufB, n);  // layer 1 sums
    fixS_k    <<<16, 256, 0, stream>>>(ovf, ovf_cnt, bufA, bufB);
    relu_k    <<<gb_n, 256, 0, stream>>>(bufB, dinv, b1, n);                   // bufB = hd
    agg_k     <<<(n + 63) / 64, 256, 0, stream>>>(og, padded, bufB, bufA, n);  // layer 2 sums
    fixS_k    <<<16, 256, 0, stream>>>(ovf, ovf_cnt, bufB, bufA);
    final_k   <<<gb_n, 256, 0, stream>>>(bufA, dinv, W2, b2, out, n);
}